// Round 5
// baseline (2054.936 us; speedup 1.0000x reference)
//
#include <hip/hip_runtime.h>

#define DIM 64
#define NN 20000
#define NE 50000
#define NG 256
#define CONV_STEPS 12
#define S2S 3

typedef float floatx4 __attribute__((ext_vector_type(4)));
typedef short short8 __attribute__((ext_vector_type(8)));

__device__ __forceinline__ unsigned short f2bf(float f) {
    unsigned u = __float_as_uint(f);
    unsigned r = (u + 0x7fffu + ((u >> 16) & 1u)) >> 16;
    return (unsigned short)r;
}
__device__ __forceinline__ float sigmoidf(float x) { return 1.f / (1.f + __expf(-x)); }
__device__ __forceinline__ float tanh_fast(float x) {
    float ax = fabsf(x);
    float t = __expf(-2.f * ax);
    float r = (1.f - t) / (1.f + t);
    return copysignf(r, x);
}
__device__ __forceinline__ float leaky(float v) { return v > 0.f ? v : 0.01f * v; }

// ---- prep: convert net_w2 to bf16, transpose GRU weights ----
__global__ __launch_bounds__(256) void prep_kernel(const float* __restrict__ w2,
        const float* __restrict__ wih, const float* __restrict__ whh,
        unsigned short* __restrict__ w2bf, float* __restrict__ wihT, float* __restrict__ whhT) {
    int idx = blockIdx.x * 256 + threadIdx.x;
    const int W2N = 4096 * 128, GT = 192 * 64;
    if (idx < W2N) {
        w2bf[idx] = f2bf(w2[idx]);
    } else if (idx < W2N + GT) {
        int t = idx - W2N; int j = t / 64, i = t % 64;
        wihT[i * 192 + j] = wih[t];
    } else if (idx < W2N + 2 * GT) {
        int t = idx - W2N - GT; int j = t / 64, i = t % 64;
        whhT[i * 192 + j] = whh[t];
    }
}

// ---- h1 = leaky(edge_attr @ net_w1.T + b1), bf16 [NE,128] ----
__global__ __launch_bounds__(256) void h1_kernel(const float* __restrict__ ea,
        const float* __restrict__ w1, const float* __restrict__ b1, unsigned short* __restrict__ h1) {
    int idx = blockIdx.x * 256 + threadIdx.x;
    if (idx >= NE * 128) return;
    int e = idx >> 7, k = idx & 127;
    const float* a = ea + (size_t)e * 4;
    const float* w = w1 + (size_t)k * 4;
    float acc = b1[k] + a[0] * w[0] + a[1] * w[1] + a[2] * w[2] + a[3] * w[3];
    h1[idx] = f2bf(leaky(acc));
}

// ---- lin0: X = leaky(x @ lin0_w.T + b), f32 [NN,64]; wave per node ----
__global__ __launch_bounds__(256) void lin0_kernel(const float* __restrict__ x,
        const float* __restrict__ w, const float* __restrict__ b, float* __restrict__ X) {
    int gid = blockIdx.x * 256 + threadIdx.x;
    int n = gid >> 6, o = gid & 63;
    if (n >= NN) return;
    float acc = b[o];
    const float* xr = x + (size_t)n * 72;
    const float* wr = w + (size_t)o * 72;
    #pragma unroll 8
    for (int i = 0; i < 72; ++i) acc += xr[i] * wr[i];
    X[(size_t)n * 64 + o] = leaky(acc);
}

// ---- degree of dst nodes ----
__global__ __launch_bounds__(256) void deg_kernel(const int* __restrict__ ei, float* __restrict__ deg) {
    int e = blockIdx.x * 256 + threadIdx.x;
    if (e < NE) atomicAdd(&deg[ei[NE + e]], 1.f);
}

// ---- per-graph node range starts (batch is sorted) ----
__global__ void gstart_kernel(const int* __restrict__ batch, int* __restrict__ gstart) {
    int g = blockIdx.x * blockDim.x + threadIdx.x;
    if (g > NG) return;
    int lo = 0, hi = NN;
    while (lo < hi) { int mid = (lo + hi) >> 1; if (batch[mid] < g) lo = mid + 1; else hi = mid; }
    gstart[g] = lo;
}

// stage one 64-row x 128-col bf16 W2 tile (16 KB) into LDS, XOR-swizzled.
// LDS dest is linear (global_load_lds writes base+lane*16); the global SOURCE
// byte within the tile is pre-swizzled with the same involution the reader
// applies: srcb = row*256 + (col ^ ((row&7)<<4)).
__device__ __forceinline__ void stage_w2(const unsigned short* __restrict__ w2, int ib,
                                         unsigned short* buf, int wv, int lane) {
    #pragma unroll
    for (int i = 0; i < 4; ++i) {
        int d0 = (i * 4 + wv) * 1024;          // wave-uniform LDS base
        int d = d0 + lane * 16;                // this lane's dest byte
        int rowl = d >> 8;                     // row within tile (256 B rows)
        int cb = d & 255;
        int srcb = rowl * 256 + (cb ^ ((rowl & 7) << 4));
        const char* g = (const char*)w2 + (size_t)ib * 16384 + srcb;
        __builtin_amdgcn_global_load_lds(
            (const __attribute__((address_space(1))) void*)g,
            (__attribute__((address_space(3))) void*)((char*)buf + d0),
            16, 0, 0);
    }
}

// ---- fused edge messages: recompute w_e tiles in registers via MFMA from an
//      LDS-shared, double-buffered W2 tile; contract against f32 X[src]
//      immediately; atomic-accumulate into agg[dst].
// grid (ceil(NE/128), 2): y = half of the input-feature (ib) range.
// block 256 thr = 4 waves; wave = (edge-half eh, o-half oh): 64 edges x 32 o.
// A-frags (h1) hoisted out of the il loop; W2 read per-wave is only its o-slice.
__global__ __launch_bounds__(256, 3) void edge_msg_fused(
        const unsigned short* __restrict__ h1,   // [NE,128] bf16
        const unsigned short* __restrict__ w2,   // [4096,128] bf16
        const float* __restrict__ b2,            // [4096] f32
        const float* __restrict__ X,             // [NN,64] f32
        const int* __restrict__ ei, float* __restrict__ agg) {
    __shared__ float xs_t[32 * 128];             // [ib_local][edge_local] 16 KB
    __shared__ unsigned short w2buf[2][8192];    // 2 x 16 KB double buffer
    int tid = threadIdx.x;
    int e0b = blockIdx.x * 128;
    int ibBase = blockIdx.y * 32;

    // stage X transposed: xs_t[f_local][e_local], f = ibBase + f_local
    {
        int e_l = tid & 127, half = tid >> 7;
        int e = e0b + e_l; if (e >= NE) e = NE - 1;
        int src = ei[e];
        const float4* xr = (const float4*)(X + (size_t)src * 64 + ibBase + half * 16);
        #pragma unroll
        for (int c = 0; c < 4; ++c) {
            float4 v = xr[c];
            int f = half * 16 + c * 4;
            xs_t[(f + 0) * 128 + e_l] = v.x;
            xs_t[(f + 1) * 128 + e_l] = v.y;
            xs_t[(f + 2) * 128 + e_l] = v.z;
            xs_t[(f + 3) * 128 + e_l] = v.w;
        }
    }

    int wv = tid >> 6, lane = tid & 63;
    int eh = wv >> 1, oh = wv & 1;               // edge-half, o-half
    int row = lane & 15, kq = lane >> 4;
    int e0w = e0b + eh * 64;

    // preload h1 A-frags ONCE: 4 m-tiles x 4 K-chunks (lane: edge=row, k=kc*32+kq*8)
    short8 afr[4][4];
    #pragma unroll
    for (int mt = 0; mt < 4; ++mt) {
        int e = e0w + mt * 16 + row; if (e >= NE) e = NE - 1;
        const short8* ap = (const short8*)(h1 + (size_t)e * 128 + kq * 8);
        #pragma unroll
        for (int kc = 0; kc < 4; ++kc) afr[mt][kc] = ap[kc * 4];
    }

    stage_w2(w2, ibBase, w2buf[0], wv, lane);
    __syncthreads();   // X-stage + first W2 tile ready (barrier drains vmcnt)

    floatx4 msg[4][2];  // [mt][ot]; lane: edge=kq*4+r, o=oh*32+ot*16+row
    #pragma unroll
    for (int mt = 0; mt < 4; ++mt)
        #pragma unroll
        for (int ot = 0; ot < 2; ++ot) msg[mt][ot] = (floatx4){0.f, 0.f, 0.f, 0.f};

    for (int il = 0; il < 32; ++il) {
        int cur = il & 1;
        if (il < 31) stage_w2(w2, ibBase + il + 1, w2buf[cur ^ 1], wv, lane);
        int ib = ibBase + il;
        // x values for this wave's 64 edges (broadcast reads, 16 lanes/addr)
        float4 xv[4];
        #pragma unroll
        for (int mt = 0; mt < 4; ++mt)
            xv[mt] = *(const float4*)&xs_t[il * 128 + eh * 64 + mt * 16 + kq * 4];
        #pragma unroll
        for (int ot = 0; ot < 2; ++ot) {
            int row_l = oh * 32 + ot * 16 + row;
            const char* bbase = (const char*)w2buf[cur] + row_l * 256;
            int sw = (row_l & 7) << 4;
            short8 bf0 = *(const short8*)(bbase + ((       0) ^ sw));
            short8 bf1 = *(const short8*)(bbase + ((kq * 16 +  64) ^ sw) - (kq * 16 ^ sw) + ((kq * 16) ^ sw) + 0); // placeholder removed below
            (void)bf1;
            short8 b0 = *(const short8*)(bbase + ((kq * 16      ) ^ sw));
            short8 b1 = *(const short8*)(bbase + ((kq * 16 +  64) ^ sw));
            short8 b2f = *(const short8*)(bbase + ((kq * 16 + 128) ^ sw));
            short8 b3 = *(const short8*)(bbase + ((kq * 16 + 192) ^ sw));
            float bias = b2[ib * 64 + row_l];
            #pragma unroll
            for (int mt = 0; mt < 4; ++mt) {
                floatx4 acc = {0.f, 0.f, 0.f, 0.f};
                acc = __builtin_amdgcn_mfma_f32_16x16x32_bf16(afr[mt][0], b0, acc, 0, 0, 0);
                acc = __builtin_amdgcn_mfma_f32_16x16x32_bf16(afr[mt][1], b1, acc, 0, 0, 0);
                acc = __builtin_amdgcn_mfma_f32_16x16x32_bf16(afr[mt][2], b2f, acc, 0, 0, 0);
                acc = __builtin_amdgcn_mfma_f32_16x16x32_bf16(afr[mt][3], b3, acc, 0, 0, 0);
                msg[mt][ot][0] += xv[mt].x * (acc[0] + bias);
                msg[mt][ot][1] += xv[mt].y * (acc[1] + bias);
                msg[mt][ot][2] += xv[mt].z * (acc[2] + bias);
                msg[mt][ot][3] += xv[mt].w * (acc[3] + bias);
            }
        }
        __syncthreads();  // all waves done with w2buf[cur]; prefetch landed
    }

    // scatter-accumulate (lane: edge = kq*4+r, o = oh*32+ot*16+row)
    #pragma unroll
    for (int mt = 0; mt < 4; ++mt) {
        #pragma unroll
        for (int r = 0; r < 4; ++r) {
            int e = e0w + mt * 16 + kq * 4 + r;
            if (e < NE) {
                int dst = ei[NE + e];
                #pragma unroll
                for (int ot = 0; ot < 2; ++ot)
                    atomicAdd(&agg[(size_t)dst * 64 + oh * 32 + ot * 16 + row], msg[mt][ot][r]);
            }
        }
    }
}

// ---- node update: m = leaky(agg/deg + X@root_w + cb); GRU(h=X, in=m) -> X; wave per 4 nodes ----
__global__ __launch_bounds__(256) void node_update(float* __restrict__ X, float* __restrict__ agg,
        const float* __restrict__ deg, const float* __restrict__ root_w, const float* __restrict__ conv_b,
        const float* __restrict__ wihT, const float* __restrict__ whhT,
        const float* __restrict__ bih, const float* __restrict__ bhh) {
    int gid = blockIdx.x * 256 + threadIdx.x;
    int wv = gid >> 6, lane = gid & 63;
    int n0 = wv * 4;
    if (n0 >= NN) return;
    float xv[4], m[4];
    #pragma unroll
    for (int t = 0; t < 4; ++t) xv[t] = X[(size_t)(n0 + t) * 64 + lane];
    float cb = conv_b[lane];
    #pragma unroll
    for (int t = 0; t < 4; ++t) {
        size_t id = (size_t)(n0 + t) * 64 + lane;
        float a = agg[id]; agg[id] = 0.f;   // re-zero for next step's atomics
        m[t] = a / fmaxf(deg[n0 + t], 1.f) + cb;
    }
    #pragma unroll 8
    for (int i = 0; i < 64; ++i) {
        float rw = root_w[i * 64 + lane];
        #pragma unroll
        for (int t = 0; t < 4; ++t) m[t] += __shfl(xv[t], i) * rw;
    }
    #pragma unroll
    for (int t = 0; t < 4; ++t) m[t] = leaky(m[t]);
    float g0[4], g1[4], g2[4], h0[4], h1g[4], h2[4];
    float bi0 = bih[lane], bi1 = bih[64 + lane], bi2 = bih[128 + lane];
    float bh0 = bhh[lane], bh1 = bhh[64 + lane], bh2 = bhh[128 + lane];
    #pragma unroll
    for (int t = 0; t < 4; ++t) { g0[t] = bi0; g1[t] = bi1; g2[t] = bi2; h0[t] = bh0; h1g[t] = bh1; h2[t] = bh2; }
    #pragma unroll 8
    for (int i = 0; i < 64; ++i) {
        float wi0 = wihT[i * 192 + lane], wi1 = wihT[i * 192 + 64 + lane], wi2 = wihT[i * 192 + 128 + lane];
        float wh0 = whhT[i * 192 + lane], wh1 = whhT[i * 192 + 64 + lane], wh2 = whhT[i * 192 + 128 + lane];
        #pragma unroll
        for (int t = 0; t < 4; ++t) {
            float mb = __shfl(m[t], i), hb = __shfl(xv[t], i);
            g0[t] += mb * wi0; g1[t] += mb * wi1; g2[t] += mb * wi2;
            h0[t] += hb * wh0; h1g[t] += hb * wh1; h2[t] += hb * wh2;
        }
    }
    #pragma unroll
    for (int t = 0; t < 4; ++t) {
        float r = sigmoidf(g0[t] + h0[t]);
        float z = sigmoidf(g1[t] + h1g[t]);
        float nn = tanh_fast(g2[t] + r * h2[t]);
        X[(size_t)(n0 + t) * 64 + lane] = (1.f - z) * nn + z * xv[t];
    }
}

// ---- set2set LSTM step; block per graph ----
__global__ __launch_bounds__(256) void lstm_kernel(const float* __restrict__ qstar,
        float* __restrict__ hl, float* __restrict__ cl,
        const float* __restrict__ wih, const float* __restrict__ whh,
        const float* __restrict__ bih, const float* __restrict__ bhh) {
    int g = blockIdx.x, tid = threadIdx.x;
    __shared__ float qs[128], hs[64], gates[256];
    if (tid < 128) qs[tid] = qstar[(size_t)g * 128 + tid];
    else if (tid < 192) hs[tid - 128] = hl[(size_t)g * 64 + tid - 128];
    __syncthreads();
    float acc = bih[tid] + bhh[tid];
    const float* wr = wih + (size_t)tid * 128;
    #pragma unroll 8
    for (int k = 0; k < 128; ++k) acc += qs[k] * wr[k];
    const float* wr2 = whh + (size_t)tid * 64;
    #pragma unroll 8
    for (int k = 0; k < 64; ++k) acc += hs[k] * wr2[k];
    gates[tid] = acc;
    __syncthreads();
    if (tid < 64) {
        float gi = gates[tid], gf = gates[64 + tid], gg = gates[128 + tid], go = gates[192 + tid];
        float c = sigmoidf(gf) * cl[(size_t)g * 64 + tid] + sigmoidf(gi) * tanh_fast(gg);
        float h = sigmoidf(go) * tanh_fast(c);
        cl[(size_t)g * 64 + tid] = c;
        hl[(size_t)g * 64 + tid] = h;
    }
}

// ---- e[n] = dot(X[n], hl[batch[n]]); wave per node ----
__global__ __launch_bounds__(256) void e_kernel(const float* __restrict__ X, const float* __restrict__ hl,
        const int* __restrict__ batch, float* __restrict__ ev) {
    int gid = blockIdx.x * 256 + threadIdx.x;
    int n = gid >> 6, lane = gid & 63;
    if (n >= NN) return;
    int g = batch[n];
    float v = X[(size_t)n * 64 + lane] * hl[(size_t)g * 64 + lane];
    #pragma unroll
    for (int m = 32; m >= 1; m >>= 1) v += __shfl_xor(v, m);
    if (lane == 0) ev[n] = v;
}

// ---- per-graph softmax-attention readout; writes q_star = [hl, r]; block per graph ----
__global__ __launch_bounds__(256) void pool_kernel(const float* __restrict__ X, const float* __restrict__ ev,
        const float* __restrict__ hl, const int* __restrict__ gstart, float* __restrict__ qstar) {
    int g = blockIdx.x, tid = threadIdx.x;
    int s0 = gstart[g], s1 = gstart[g + 1];
    __shared__ float red[256];
    __shared__ float sh_max, sh_sum;
    float lm = -3.0e38f;
    for (int n = s0 + tid; n < s1; n += 256) lm = fmaxf(lm, ev[n]);
    red[tid] = lm; __syncthreads();
    for (int s = 128; s > 0; s >>= 1) { if (tid < s) red[tid] = fmaxf(red[tid], red[tid + s]); __syncthreads(); }
    if (tid == 0) sh_max = red[0];
    __syncthreads();
    float mx = sh_max;
    float ls = 0.f;
    for (int n = s0 + tid; n < s1; n += 256) ls += __expf(ev[n] - mx);
    __syncthreads();
    red[tid] = ls; __syncthreads();
    for (int s = 128; s > 0; s >>= 1) { if (tid < s) red[tid] += red[tid + s]; __syncthreads(); }
    if (tid == 0) sh_sum = red[0];
    __syncthreads();
    float inv = 1.f / (sh_sum + 1e-16f);
    int wv = tid >> 6, lane = tid & 63;
    float fa = 0.f;
    for (int n = s0 + wv; n < s1; n += 4) fa += __expf(ev[n] - mx) * inv * X[(size_t)n * 64 + lane];
    __syncthreads();
    red[tid] = fa; __syncthreads();
    if (tid < 64) {
        float r = red[tid] + red[64 + tid] + red[128 + tid] + red[192 + tid];
        qstar[(size_t)g * 128 + 64 + tid] = r;
        qstar[(size_t)g * 128 + tid] = hl[(size_t)g * 64 + tid];
    }
}

// ---- final: out[g] = q_star[g] . lin3_w + b ----
__global__ __launch_bounds__(256) void final_kernel(const float* __restrict__ qstar,
        const float* __restrict__ w3, const float* __restrict__ b3, float* __restrict__ out) {
    int gid = blockIdx.x * 256 + threadIdx.x;
    int g = gid >> 6, lane = gid & 63;
    if (g >= NG) return;
    float v = qstar[(size_t)g * 128 + lane] * w3[lane] + qstar[(size_t)g * 128 + 64 + lane] * w3[64 + lane];
    #pragma unroll
    for (int m = 32; m >= 1; m >>= 1) v += __shfl_xor(v, m);
    if (lane == 0) out[g] = v + b3[0];
}

extern "C" void kernel_launch(void* const* d_in, const int* in_sizes, int n_in,
                              void* d_out, int out_size, void* d_ws, size_t ws_size,
                              hipStream_t stream) {
    const float* x        = (const float*)d_in[0];
    const float* ea       = (const float*)d_in[1];
    const int*   ei       = (const int*)d_in[2];
    const int*   batch    = (const int*)d_in[3];
    const float* lin0_w   = (const float*)d_in[4];
    const float* lin0_b   = (const float*)d_in[5];
    const float* net_w1   = (const float*)d_in[6];
    const float* net_b1   = (const float*)d_in[7];
    const float* net_w2   = (const float*)d_in[8];
    const float* net_b2   = (const float*)d_in[9];
    const float* root_w   = (const float*)d_in[10];
    const float* conv_b   = (const float*)d_in[11];
    const float* gru_w_ih = (const float*)d_in[12];
    const float* gru_w_hh = (const float*)d_in[13];
    const float* gru_b_ih = (const float*)d_in[14];
    const float* gru_b_hh = (const float*)d_in[15];
    const float* lstm_w_ih= (const float*)d_in[16];
    const float* lstm_w_hh= (const float*)d_in[17];
    const float* lstm_b_ih= (const float*)d_in[18];
    const float* lstm_b_hh= (const float*)d_in[19];
    const float* lin3_w   = (const float*)d_in[20];
    const float* lin3_b   = (const float*)d_in[21];
    float* out = (float*)d_out;

    char* base = (char*)d_ws;
    size_t off = 0;
    auto alloc = [&](size_t b) { size_t o = off; off += (b + 255) & ~(size_t)255; return o; };
    size_t o_h1    = alloc((size_t)NE * 128 * 2);
    size_t o_X     = alloc((size_t)NN * 64 * 4);
    size_t o_agg   = alloc((size_t)NN * 64 * 4);
    size_t o_deg   = alloc((size_t)NN * 4);
    size_t o_ev    = alloc((size_t)NN * 4);
    size_t o_s2s   = alloc((size_t)(NG * 128 + NG * 64 + NG * 64) * 4);  // qstar | hl | cl
    size_t o_gst   = alloc((size_t)(NG + 1) * 4);
    size_t o_w2bf  = alloc((size_t)4096 * 128 * 2);
    size_t o_wihT  = alloc((size_t)192 * 64 * 4);
    size_t o_whhT  = alloc((size_t)192 * 64 * 4);
    if (ws_size < off) return;  // needs ~26 MB

    unsigned short* h1   = (unsigned short*)(base + o_h1);
    float* X    = (float*)(base + o_X);
    float* agg  = (float*)(base + o_agg);
    float* deg  = (float*)(base + o_deg);
    float* ev   = (float*)(base + o_ev);
    float* qstar= (float*)(base + o_s2s);
    float* hl   = qstar + NG * 128;
    float* cl   = hl + NG * 64;
    int*   gst  = (int*)(base + o_gst);
    unsigned short* w2bf = (unsigned short*)(base + o_w2bf);
    float* wihT = (float*)(base + o_wihT);
    float* whhT = (float*)(base + o_whhT);

    hipMemsetAsync(deg, 0, (size_t)NN * 4, stream);
    hipMemsetAsync(agg, 0, (size_t)NN * 64 * 4, stream);
    hipMemsetAsync(qstar, 0, (size_t)(NG * 128 + NG * 64 + NG * 64) * 4, stream);

    prep_kernel<<<(4096 * 128 + 2 * 192 * 64 + 255) / 256, 256, 0, stream>>>(
        net_w2, gru_w_ih, gru_w_hh, w2bf, wihT, whhT);
    h1_kernel<<<(NE * 128 + 255) / 256, 256, 0, stream>>>(ea, net_w1, net_b1, h1);
    lin0_kernel<<<(NN * 64 + 255) / 256, 256, 0, stream>>>(x, lin0_w, lin0_b, X);
    deg_kernel<<<(NE + 255) / 256, 256, 0, stream>>>(ei, deg);
    gstart_kernel<<<2, 256, 0, stream>>>(batch, gst);

    const dim3 EGRID((NE + 127) / 128, 2);
    for (int s = 0; s < CONV_STEPS; ++s) {
        edge_msg_fused<<<EGRID, 256, 0, stream>>>(h1, w2bf, net_b2, X, ei, agg);
        node_update<<<(NN / 4 * 64 + 255) / 256, 256, 0, stream>>>(
            X, agg, deg, root_w, conv_b, wihT, whhT, gru_b_ih, gru_b_hh);
    }

    for (int s = 0; s < S2S; ++s) {
        lstm_kernel<<<NG, 256, 0, stream>>>(qstar, hl, cl, lstm_w_ih, lstm_w_hh, lstm_b_ih, lstm_b_hh);
        e_kernel<<<(NN * 64 + 255) / 256, 256, 0, stream>>>(X, hl, batch, ev);
        pool_kernel<<<NG, 256, 0, stream>>>(X, ev, hl, gst, qstar);
    }
    final_kernel<<<(NG * 64 + 255) / 256, 256, 0, stream>>>(qstar, lin3_w, lin3_b, out);
}

// Round 6
// 1888.406 us; speedup vs baseline: 1.0882x; 1.0882x over previous
//
#include <hip/hip_runtime.h>

#define DIM 64
#define NN 20000
#define NE 50000
#define NG 256
#define CONV_STEPS 12
#define S2S 3

typedef float floatx4 __attribute__((ext_vector_type(4)));
typedef short short8 __attribute__((ext_vector_type(8)));

__device__ __forceinline__ unsigned short f2bf(float f) {
    unsigned u = __float_as_uint(f);
    unsigned r = (u + 0x7fffu + ((u >> 16) & 1u)) >> 16;
    return (unsigned short)r;
}
__device__ __forceinline__ float sigmoidf(float x) { return 1.f / (1.f + __expf(-x)); }
__device__ __forceinline__ float tanh_fast(float x) {
    float ax = fabsf(x);
    float t = __expf(-2.f * ax);
    float r = (1.f - t) / (1.f + t);
    return copysignf(r, x);
}
__device__ __forceinline__ float leaky(float v) { return v > 0.f ? v : 0.01f * v; }

// ---- prep: convert net_w2 to bf16, transpose GRU weights ----
__global__ __launch_bounds__(256) void prep_kernel(const float* __restrict__ w2,
        const float* __restrict__ wih, const float* __restrict__ whh,
        unsigned short* __restrict__ w2bf, float* __restrict__ wihT, float* __restrict__ whhT) {
    int idx = blockIdx.x * 256 + threadIdx.x;
    const int W2N = 4096 * 128, GT = 192 * 64;
    if (idx < W2N) {
        w2bf[idx] = f2bf(w2[idx]);
    } else if (idx < W2N + GT) {
        int t = idx - W2N; int j = t / 64, i = t % 64;
        wihT[i * 192 + j] = wih[t];
    } else if (idx < W2N + 2 * GT) {
        int t = idx - W2N - GT; int j = t / 64, i = t % 64;
        whhT[i * 192 + j] = whh[t];
    }
}

// ---- h1 = leaky(edge_attr @ net_w1.T + b1), bf16 [NE,128] ----
__global__ __launch_bounds__(256) void h1_kernel(const float* __restrict__ ea,
        const float* __restrict__ w1, const float* __restrict__ b1, unsigned short* __restrict__ h1) {
    int idx = blockIdx.x * 256 + threadIdx.x;
    if (idx >= NE * 128) return;
    int e = idx >> 7, k = idx & 127;
    const float* a = ea + (size_t)e * 4;
    const float* w = w1 + (size_t)k * 4;
    float acc = b1[k] + a[0] * w[0] + a[1] * w[1] + a[2] * w[2] + a[3] * w[3];
    h1[idx] = f2bf(leaky(acc));
}

// ---- lin0: X = leaky(x @ lin0_w.T + b), f32 [NN,64]; wave per node ----
__global__ __launch_bounds__(256) void lin0_kernel(const float* __restrict__ x,
        const float* __restrict__ w, const float* __restrict__ b, float* __restrict__ X) {
    int gid = blockIdx.x * 256 + threadIdx.x;
    int n = gid >> 6, o = gid & 63;
    if (n >= NN) return;
    float acc = b[o];
    const float* xr = x + (size_t)n * 72;
    const float* wr = w + (size_t)o * 72;
    #pragma unroll 8
    for (int i = 0; i < 72; ++i) acc += xr[i] * wr[i];
    X[(size_t)n * 64 + o] = leaky(acc);
}

// ---- degree of dst nodes ----
__global__ __launch_bounds__(256) void deg_kernel(const int* __restrict__ ei, float* __restrict__ deg) {
    int e = blockIdx.x * 256 + threadIdx.x;
    if (e < NE) atomicAdd(&deg[ei[NE + e]], 1.f);
}

// ---- per-graph node range starts (batch is sorted) ----
__global__ void gstart_kernel(const int* __restrict__ batch, int* __restrict__ gstart) {
    int g = blockIdx.x * blockDim.x + threadIdx.x;
    if (g > NG) return;
    int lo = 0, hi = NN;
    while (lo < hi) { int mid = (lo + hi) >> 1; if (batch[mid] < g) lo = mid + 1; else hi = mid; }
    gstart[g] = lo;
}

// stage one 64-row x 128-col bf16 W2 tile (16 KB) into LDS, XOR-swizzled.
// LDS dest is linear (global_load_lds writes base+lane*16); the global SOURCE
// byte within the tile is pre-swizzled with the same involution the reader
// applies: srcb = row*256 + (col ^ ((row&7)<<4)).  4 loads per wave.
__device__ __forceinline__ void stage_w2(const unsigned short* __restrict__ w2, int ib,
                                         unsigned short* buf, int wv, int lane) {
    #pragma unroll
    for (int i = 0; i < 4; ++i) {
        int d0 = (i * 4 + wv) * 1024;          // wave-uniform LDS base
        int d = d0 + lane * 16;                // this lane's dest byte
        int rowl = d >> 8;                     // row within tile (256 B rows)
        int cb = d & 255;
        int srcb = rowl * 256 + (cb ^ ((rowl & 7) << 4));
        const char* g = (const char*)w2 + (size_t)ib * 16384 + srcb;
        __builtin_amdgcn_global_load_lds(
            (const __attribute__((address_space(1))) void*)g,
            (__attribute__((address_space(3))) void*)((char*)buf + d0),
            16, 0, 0);
    }
}

// ---- fused edge messages: recompute w_e tiles in registers via MFMA from an
//      LDS-shared, double-buffered W2 tile; contract against f32 X[src]
//      immediately; atomic-accumulate into agg[dst].
// grid (ceil(NE/128), 2): y = half of the input-feature (ib) range.
// block 256 thr = 4 waves; wave = 32 edges (2 m-tiles of 16) x all 64 o.
// Pipeline: raw s_barrier + counted vmcnt (never drain the prefetch queue).
__global__ __launch_bounds__(256) void edge_msg_fused(
        const unsigned short* __restrict__ h1,   // [NE,128] bf16
        const unsigned short* __restrict__ w2,   // [4096,128] bf16
        const float* __restrict__ b2,            // [4096] f32
        const float* __restrict__ X,             // [NN,64] f32
        const int* __restrict__ ei, float* __restrict__ agg) {
    __shared__ float xs_t[32 * 128];             // [ib_local][edge_local] 16 KB
    __shared__ unsigned short w2buf[2][8192];    // 2 x 16 KB double buffer
    int tid = threadIdx.x;
    int e0b = blockIdx.x * 128;
    int ibBase = blockIdx.y * 32;

    // stage X transposed: xs_t[f_local][e_local], f = ibBase + f_local
    {
        int e_l = tid & 127, half = tid >> 7;
        int e = e0b + e_l; if (e >= NE) e = NE - 1;
        int src = ei[e];
        const float4* xr = (const float4*)(X + (size_t)src * 64 + ibBase + half * 16);
        #pragma unroll
        for (int c = 0; c < 4; ++c) {
            float4 v = xr[c];
            int f = half * 16 + c * 4;
            xs_t[(f + 0) * 128 + e_l] = v.x;
            xs_t[(f + 1) * 128 + e_l] = v.y;
            xs_t[(f + 2) * 128 + e_l] = v.z;
            xs_t[(f + 3) * 128 + e_l] = v.w;
        }
    }

    int wv = tid >> 6, lane = tid & 63;
    int row = lane & 15, kq = lane >> 4;
    int e0w = e0b + wv * 32;

    // preload h1 A-frags: 2 m-tiles x 4 K-chunks (lane: edge=row, k=kc*32+kq*8)
    short8 afr[2][4];
    #pragma unroll
    for (int mt = 0; mt < 2; ++mt) {
        int e = e0w + mt * 16 + row; if (e >= NE) e = NE - 1;
        const short8* ap = (const short8*)(h1 + (size_t)e * 128 + kq * 8);
        #pragma unroll
        for (int kc = 0; kc < 4; ++kc) afr[mt][kc] = ap[kc * 4];
    }

    __syncthreads();                     // xs_t visible (full drain — prologue only)
    stage_w2(w2, ibBase + 0, w2buf[0], wv, lane);
    stage_w2(w2, ibBase + 1, w2buf[1], wv, lane);
    asm volatile("s_waitcnt vmcnt(4)" ::: "memory");   // tile 0 landed (tile 1 in flight)
    __builtin_amdgcn_s_barrier();
    __builtin_amdgcn_sched_barrier(0);

    floatx4 msg[2][4];  // [mt][ot]; lane: edge=kq*4+r, o=ot*16+row
    #pragma unroll
    for (int mt = 0; mt < 2; ++mt)
        #pragma unroll
        for (int ot = 0; ot < 4; ++ot) msg[mt][ot] = (floatx4){0.f, 0.f, 0.f, 0.f};

    for (int il = 0; il < 32; ++il) {
        int cur = il & 1;
        int ib = ibBase + il;
        float4 xv[2];
        #pragma unroll
        for (int mt = 0; mt < 2; ++mt)
            xv[mt] = *(const float4*)&xs_t[il * 128 + wv * 32 + mt * 16 + kq * 4];
        #pragma unroll
        for (int ot = 0; ot < 4; ++ot) {
            int row_l = ot * 16 + row;
            const char* bbase = (const char*)w2buf[cur] + row_l * 256;
            int sw = (row_l & 7) << 4;
            short8 b0 = *(const short8*)(bbase + ((kq * 16      ) ^ sw));
            short8 b1 = *(const short8*)(bbase + ((kq * 16 +  64) ^ sw));
            short8 b2f = *(const short8*)(bbase + ((kq * 16 + 128) ^ sw));
            short8 b3 = *(const short8*)(bbase + ((kq * 16 + 192) ^ sw));
            float bias = b2[ib * 64 + row_l];
            #pragma unroll
            for (int mt = 0; mt < 2; ++mt) {
                floatx4 acc = {0.f, 0.f, 0.f, 0.f};
                acc = __builtin_amdgcn_mfma_f32_16x16x32_bf16(afr[mt][0], b0, acc, 0, 0, 0);
                acc = __builtin_amdgcn_mfma_f32_16x16x32_bf16(afr[mt][1], b1, acc, 0, 0, 0);
                acc = __builtin_amdgcn_mfma_f32_16x16x32_bf16(afr[mt][2], b2f, acc, 0, 0, 0);
                acc = __builtin_amdgcn_mfma_f32_16x16x32_bf16(afr[mt][3], b3, acc, 0, 0, 0);
                msg[mt][ot][0] += xv[mt].x * (acc[0] + bias);
                msg[mt][ot][1] += xv[mt].y * (acc[1] + bias);
                msg[mt][ot][2] += xv[mt].z * (acc[2] + bias);
                msg[mt][ot][3] += xv[mt].w * (acc[3] + bias);
            }
        }
        if (il < 31) {
            // release buf[cur] (all waves finished reading it)
            __builtin_amdgcn_sched_barrier(0);
            __builtin_amdgcn_s_barrier();
            __builtin_amdgcn_sched_barrier(0);
            if (il + 2 < 32) {
                stage_w2(w2, ibBase + il + 2, w2buf[cur], wv, lane);
                asm volatile("s_waitcnt vmcnt(4)" ::: "memory");  // tile il+1 landed; il+2 stays in flight
            } else {
                asm volatile("s_waitcnt vmcnt(0)" ::: "memory");  // tail: only tile il+1 outstanding
            }
            __builtin_amdgcn_s_barrier();          // tile il+1 ready for all waves
            __builtin_amdgcn_sched_barrier(0);
        }
    }

    // scatter-accumulate (lane: edge = kq*4+r, o = ot*16+row)
    #pragma unroll
    for (int mt = 0; mt < 2; ++mt) {
        #pragma unroll
        for (int r = 0; r < 4; ++r) {
            int e = e0w + mt * 16 + kq * 4 + r;
            if (e < NE) {
                int dst = ei[NE + e];
                #pragma unroll
                for (int ot = 0; ot < 4; ++ot)
                    atomicAdd(&agg[(size_t)dst * 64 + ot * 16 + row], msg[mt][ot][r]);
            }
        }
    }
}

// ---- node update: m = leaky(agg/deg + X@root_w + cb); GRU(h=X, in=m) -> X; wave per 4 nodes ----
__global__ __launch_bounds__(256) void node_update(float* __restrict__ X, float* __restrict__ agg,
        const float* __restrict__ deg, const float* __restrict__ root_w, const float* __restrict__ conv_b,
        const float* __restrict__ wihT, const float* __restrict__ whhT,
        const float* __restrict__ bih, const float* __restrict__ bhh) {
    int gid = blockIdx.x * 256 + threadIdx.x;
    int wv = gid >> 6, lane = gid & 63;
    int n0 = wv * 4;
    if (n0 >= NN) return;
    float xv[4], m[4];
    #pragma unroll
    for (int t = 0; t < 4; ++t) xv[t] = X[(size_t)(n0 + t) * 64 + lane];
    float cb = conv_b[lane];
    #pragma unroll
    for (int t = 0; t < 4; ++t) {
        size_t id = (size_t)(n0 + t) * 64 + lane;
        float a = agg[id]; agg[id] = 0.f;   // re-zero for next step's atomics
        m[t] = a / fmaxf(deg[n0 + t], 1.f) + cb;
    }
    #pragma unroll 8
    for (int i = 0; i < 64; ++i) {
        float rw = root_w[i * 64 + lane];
        #pragma unroll
        for (int t = 0; t < 4; ++t) m[t] += __shfl(xv[t], i) * rw;
    }
    #pragma unroll
    for (int t = 0; t < 4; ++t) m[t] = leaky(m[t]);
    float g0[4], g1[4], g2[4], h0[4], h1g[4], h2[4];
    float bi0 = bih[lane], bi1 = bih[64 + lane], bi2 = bih[128 + lane];
    float bh0 = bhh[lane], bh1 = bhh[64 + lane], bh2 = bhh[128 + lane];
    #pragma unroll
    for (int t = 0; t < 4; ++t) { g0[t] = bi0; g1[t] = bi1; g2[t] = bi2; h0[t] = bh0; h1g[t] = bh1; h2[t] = bh2; }
    #pragma unroll 8
    for (int i = 0; i < 64; ++i) {
        float wi0 = wihT[i * 192 + lane], wi1 = wihT[i * 192 + 64 + lane], wi2 = wihT[i * 192 + 128 + lane];
        float wh0 = whhT[i * 192 + lane], wh1 = whhT[i * 192 + 64 + lane], wh2 = whhT[i * 192 + 128 + lane];
        #pragma unroll
        for (int t = 0; t < 4; ++t) {
            float mb = __shfl(m[t], i), hb = __shfl(xv[t], i);
            g0[t] += mb * wi0; g1[t] += mb * wi1; g2[t] += mb * wi2;
            h0[t] += hb * wh0; h1g[t] += hb * wh1; h2[t] += hb * wh2;
        }
    }
    #pragma unroll
    for (int t = 0; t < 4; ++t) {
        float r = sigmoidf(g0[t] + h0[t]);
        float z = sigmoidf(g1[t] + h1g[t]);
        float nn = tanh_fast(g2[t] + r * h2[t]);
        X[(size_t)(n0 + t) * 64 + lane] = (1.f - z) * nn + z * xv[t];
    }
}

// ---- set2set LSTM step; block per graph ----
__global__ __launch_bounds__(256) void lstm_kernel(const float* __restrict__ qstar,
        float* __restrict__ hl, float* __restrict__ cl,
        const float* __restrict__ wih, const float* __restrict__ whh,
        const float* __restrict__ bih, const float* __restrict__ bhh) {
    int g = blockIdx.x, tid = threadIdx.x;
    __shared__ float qs[128], hs[64], gates[256];
    if (tid < 128) qs[tid] = qstar[(size_t)g * 128 + tid];
    else if (tid < 192) hs[tid - 128] = hl[(size_t)g * 64 + tid - 128];
    __syncthreads();
    float acc = bih[tid] + bhh[tid];
    const float* wr = wih + (size_t)tid * 128;
    #pragma unroll 8
    for (int k = 0; k < 128; ++k) acc += qs[k] * wr[k];
    const float* wr2 = whh + (size_t)tid * 64;
    #pragma unroll 8
    for (int k = 0; k < 64; ++k) acc += hs[k] * wr2[k];
    gates[tid] = acc;
    __syncthreads();
    if (tid < 64) {
        float gi = gates[tid], gf = gates[64 + tid], gg = gates[128 + tid], go = gates[192 + tid];
        float c = sigmoidf(gf) * cl[(size_t)g * 64 + tid] + sigmoidf(gi) * tanh_fast(gg);
        float h = sigmoidf(go) * tanh_fast(c);
        cl[(size_t)g * 64 + tid] = c;
        hl[(size_t)g * 64 + tid] = h;
    }
}

// ---- e[n] = dot(X[n], hl[batch[n]]); wave per node ----
__global__ __launch_bounds__(256) void e_kernel(const float* __restrict__ X, const float* __restrict__ hl,
        const int* __restrict__ batch, float* __restrict__ ev) {
    int gid = blockIdx.x * 256 + threadIdx.x;
    int n = gid >> 6, lane = gid & 63;
    if (n >= NN) return;
    int g = batch[n];
    float v = X[(size_t)n * 64 + lane] * hl[(size_t)g * 64 + lane];
    #pragma unroll
    for (int m = 32; m >= 1; m >>= 1) v += __shfl_xor(v, m);
    if (lane == 0) ev[n] = v;
}

// ---- per-graph softmax-attention readout; writes q_star = [hl, r]; block per graph ----
__global__ __launch_bounds__(256) void pool_kernel(const float* __restrict__ X, const float* __restrict__ ev,
        const float* __restrict__ hl, const int* __restrict__ gstart, float* __restrict__ qstar) {
    int g = blockIdx.x, tid = threadIdx.x;
    int s0 = gstart[g], s1 = gstart[g + 1];
    __shared__ float red[256];
    __shared__ float sh_max, sh_sum;
    float lm = -3.0e38f;
    for (int n = s0 + tid; n < s1; n += 256) lm = fmaxf(lm, ev[n]);
    red[tid] = lm; __syncthreads();
    for (int s = 128; s > 0; s >>= 1) { if (tid < s) red[tid] = fmaxf(red[tid], red[tid + s]); __syncthreads(); }
    if (tid == 0) sh_max = red[0];
    __syncthreads();
    float mx = sh_max;
    float ls = 0.f;
    for (int n = s0 + tid; n < s1; n += 256) ls += __expf(ev[n] - mx);
    __syncthreads();
    red[tid] = ls; __syncthreads();
    for (int s = 128; s > 0; s >>= 1) { if (tid < s) red[tid] += red[tid + s]; __syncthreads(); }
    if (tid == 0) sh_sum = red[0];
    __syncthreads();
    float inv = 1.f / (sh_sum + 1e-16f);
    int wv = tid >> 6, lane = tid & 63;
    float fa = 0.f;
    for (int n = s0 + wv; n < s1; n += 4) fa += __expf(ev[n] - mx) * inv * X[(size_t)n * 64 + lane];
    __syncthreads();
    red[tid] = fa; __syncthreads();
    if (tid < 64) {
        float r = red[tid] + red[64 + tid] + red[128 + tid] + red[192 + tid];
        qstar[(size_t)g * 128 + 64 + tid] = r;
        qstar[(size_t)g * 128 + tid] = hl[(size_t)g * 64 + tid];
    }
}

// ---- final: out[g] = q_star[g] . lin3_w + b ----
__global__ __launch_bounds__(256) void final_kernel(const float* __restrict__ qstar,
        const float* __restrict__ w3, const float* __restrict__ b3, float* __restrict__ out) {
    int gid = blockIdx.x * 256 + threadIdx.x;
    int g = gid >> 6, lane = gid & 63;
    if (g >= NG) return;
    float v = qstar[(size_t)g * 128 + lane] * w3[lane] + qstar[(size_t)g * 128 + 64 + lane] * w3[64 + lane];
    #pragma unroll
    for (int m = 32; m >= 1; m >>= 1) v += __shfl_xor(v, m);
    if (lane == 0) out[g] = v + b3[0];
}

extern "C" void kernel_launch(void* const* d_in, const int* in_sizes, int n_in,
                              void* d_out, int out_size, void* d_ws, size_t ws_size,
                              hipStream_t stream) {
    const float* x        = (const float*)d_in[0];
    const float* ea       = (const float*)d_in[1];
    const int*   ei       = (const int*)d_in[2];
    const int*   batch    = (const int*)d_in[3];
    const float* lin0_w   = (const float*)d_in[4];
    const float* lin0_b   = (const float*)d_in[5];
    const float* net_w1   = (const float*)d_in[6];
    const float* net_b1   = (const float*)d_in[7];
    const float* net_w2   = (const float*)d_in[8];
    const float* net_b2   = (const float*)d_in[9];
    const float* root_w   = (const float*)d_in[10];
    const float* conv_b   = (const float*)d_in[11];
    const float* gru_w_ih = (const float*)d_in[12];
    const float* gru_w_hh = (const float*)d_in[13];
    const float* gru_b_ih = (const float*)d_in[14];
    const float* gru_b_hh = (const float*)d_in[15];
    const float* lstm_w_ih= (const float*)d_in[16];
    const float* lstm_w_hh= (const float*)d_in[17];
    const float* lstm_b_ih= (const float*)d_in[18];
    const float* lstm_b_hh= (const float*)d_in[19];
    const float* lin3_w   = (const float*)d_in[20];
    const float* lin3_b   = (const float*)d_in[21];
    float* out = (float*)d_out;

    char* base = (char*)d_ws;
    size_t off = 0;
    auto alloc = [&](size_t b) { size_t o = off; off += (b + 255) & ~(size_t)255; return o; };
    size_t o_h1    = alloc((size_t)NE * 128 * 2);
    size_t o_X     = alloc((size_t)NN * 64 * 4);
    size_t o_agg   = alloc((size_t)NN * 64 * 4);
    size_t o_deg   = alloc((size_t)NN * 4);
    size_t o_ev    = alloc((size_t)NN * 4);
    size_t o_s2s   = alloc((size_t)(NG * 128 + NG * 64 + NG * 64) * 4);  // qstar | hl | cl
    size_t o_gst   = alloc((size_t)(NG + 1) * 4);
    size_t o_w2bf  = alloc((size_t)4096 * 128 * 2);
    size_t o_wihT  = alloc((size_t)192 * 64 * 4);
    size_t o_whhT  = alloc((size_t)192 * 64 * 4);
    if (ws_size < off) return;  // needs ~26 MB

    unsigned short* h1   = (unsigned short*)(base + o_h1);
    float* X    = (float*)(base + o_X);
    float* agg  = (float*)(base + o_agg);
    float* deg  = (float*)(base + o_deg);
    float* ev   = (float*)(base + o_ev);
    float* qstar= (float*)(base + o_s2s);
    float* hl   = qstar + NG * 128;
    float* cl   = hl + NG * 64;
    int*   gst  = (int*)(base + o_gst);
    unsigned short* w2bf = (unsigned short*)(base + o_w2bf);
    float* wihT = (float*)(base + o_wihT);
    float* whhT = (float*)(base + o_whhT);

    hipMemsetAsync(deg, 0, (size_t)NN * 4, stream);
    hipMemsetAsync(agg, 0, (size_t)NN * 64 * 4, stream);
    hipMemsetAsync(qstar, 0, (size_t)(NG * 128 + NG * 64 + NG * 64) * 4, stream);

    prep_kernel<<<(4096 * 128 + 2 * 192 * 64 + 255) / 256, 256, 0, stream>>>(
        net_w2, gru_w_ih, gru_w_hh, w2bf, wihT, whhT);
    h1_kernel<<<(NE * 128 + 255) / 256, 256, 0, stream>>>(ea, net_w1, net_b1, h1);
    lin0_kernel<<<(NN * 64 + 255) / 256, 256, 0, stream>>>(x, lin0_w, lin0_b, X);
    deg_kernel<<<(NE + 255) / 256, 256, 0, stream>>>(ei, deg);
    gstart_kernel<<<2, 256, 0, stream>>>(batch, gst);

    const dim3 EGRID((NE + 127) / 128, 2);
    for (int s = 0; s < CONV_STEPS; ++s) {
        edge_msg_fused<<<EGRID, 256, 0, stream>>>(h1, w2bf, net_b2, X, ei, agg);
        node_update<<<(NN / 4 * 64 + 255) / 256, 256, 0, stream>>>(
            X, agg, deg, root_w, conv_b, wihT, whhT, gru_b_ih, gru_b_hh);
    }

    for (int s = 0; s < S2S; ++s) {
        lstm_kernel<<<NG, 256, 0, stream>>>(qstar, hl, cl, lstm_w_ih, lstm_w_hh, lstm_b_ih, lstm_b_hh);
        e_kernel<<<(NN * 64 + 255) / 256, 256, 0, stream>>>(X, hl, batch, ev);
        pool_kernel<<<NG, 256, 0, stream>>>(X, ev, hl, gst, qstar);
    }
    final_kernel<<<(NG * 64 + 255) / 256, 256, 0, stream>>>(qstar, lin3_w, lin3_b, out);
}